// Round 14
// baseline (434.173 us; speedup 1.0000x reference)
//
#include <hip/hip_runtime.h>

// Jitter: out[b,c,t] = x[b,c,g[t]], g[t] = replace_mask[t] ? neighbor(t) : t
// neighbor(t): t==0 -> 1 ; t==T-1 -> T-2 ; else t + (neighbor_bits[t]>0 ? 1 : -1)
//
// Block-per-row variant: grid = (rows), 256 threads, 4 unrolled chunk
// iterations (t4 = iter*256 + tid). Same shuffle-fixup core as the proven
// Round-13 kernel: one coalesced float4 load, in-register neighbor fixup via
// __shfl_up/__shfl_down, predicated scalar loads at wave edges (L1-hit).
// Consecutive lanes own consecutive t4 in every iteration, so wave-adjacency
// and edge handling are identical to the validated version.

__global__ __launch_bounds__(256) void Jitter_84765474553865_kernel(
    const float* __restrict__ x,
    const int*   __restrict__ replace_mask,
    const int*   __restrict__ neighbor_bits,
    float*       __restrict__ out,
    int T, int T4 /* = T/4 */)
{
    const long long row = blockIdx.x;            // one (b,c) row per block
    const int tid  = threadIdx.x;
    const int lane = tid & 63;

    const float* __restrict__ xrow = x + row * (long long)T;
    float*       __restrict__ orow = out + row * (long long)T;

#pragma unroll 4
    for (int iter = 0; iter < 4; ++iter) {
        const int t4 = iter * 256 + tid;
        if (t4 >= T4) continue;                  // only last wave of iter 3 masks
        const int t0 = t4 * 4;

        float4 v = *reinterpret_cast<const float4*>(xrow + t0);        // coalesced 16B
        int4   m = *reinterpret_cast<const int4*>(replace_mask + t0);  // L2-resident tables
        int4   b = *reinterpret_cast<const int4*>(neighbor_bits + t0);

        float left  = __shfl_up(v.w, 1);    // element t0-1 (prev lane's v.w)
        float right = __shfl_down(v.x, 1);  // element t0+4 (next lane's v.x)
        if (lane == 0)  left  = xrow[t0 > 0 ? t0 - 1 : 0];        // wave edge
        if (lane == 63) right = xrow[t0 + 4 < T ? t0 + 4 : T - 1];// wave edge

        // j=0: t==0 -> v.y ; off=+1 -> v.y ; off=-1 -> left
        float o0 = m.x ? ((t0 == 0 || b.x > 0) ? v.y : left)  : v.x;
        // j=1: off=+1 -> v.z ; off=-1 -> v.x
        float o1 = m.y ? ((b.y > 0) ? v.z : v.x)              : v.y;
        // j=2: off=+1 -> v.w ; off=-1 -> v.y
        float o2 = m.z ? ((b.z > 0) ? v.w : v.y)              : v.z;
        // j=3: t==T-1 -> v.z (=T-2) ; off=-1 -> v.z ; off=+1 -> right
        float o3 = m.w ? ((t0 + 4 == T || b.w <= 0) ? v.z : right) : v.w;

        *reinterpret_cast<float4*>(orow + t0) = float4{o0, o1, o2, o3};
    }
}

extern "C" void kernel_launch(void* const* d_in, const int* in_sizes, int n_in,
                              void* d_out, int out_size, void* d_ws, size_t ws_size,
                              hipStream_t stream) {
    const float* x             = (const float*)d_in[0];
    const int*   replace_mask  = (const int*)d_in[1];
    const int*   neighbor_bits = (const int*)d_in[2];
    float*       out           = (float*)d_out;

    const int T    = in_sizes[1];          // 4000
    const int rows = in_sizes[0] / T;      // B*C = 16384
    const int T4   = T / 4;                // 1000

    dim3 block(256, 1, 1);
    dim3 grid(rows, 1, 1);                 // one block per (b,c) row
    Jitter_84765474553865_kernel<<<grid, block, 0, stream>>>(
        x, replace_mask, neighbor_bits, out, T, T4);
}

// Round 15
// 415.456 us; speedup vs baseline: 1.0451x; 1.0451x over previous
//
#include <hip/hip_runtime.h>

// Jitter: out[b,c,t] = x[b,c,g[t]], g[t] = replace_mask[t] ? neighbor(t) : t
// neighbor(t): t==0 -> 1 ; t==T-1 -> T-2 ; else t + (neighbor_bits[t]>0 ? 1 : -1)
//
// Structure: one coalesced float4 load per lane (64 lanes = 1KB contiguous),
// then branchless in-register fixup. All gather targets lie in [t0-1, t0+4]:
//   t0-1 = prev lane's v.w (__shfl_up), t0+4 = next lane's v.x (__shfl_down),
//   everything else is within this lane's own float4.
// Wave-edge lanes (0/63) fall back to a predicated scalar load (L1/L2-hit).
// T%4==0 and T-1 ≡ 3 (mod 4), so t==0 only occurs at j=0 and t==T-1 only at j=3.
//
// Best-measured variant (R13: 416.4 µs total). Block-per-row (R14: 434.2 µs)
// and 4-scalar-gather (R9: 433.8 µs) both regressed vs this structure.

__global__ __launch_bounds__(256) void Jitter_84765474553865_kernel(
    const float* __restrict__ x,
    const int*   __restrict__ replace_mask,
    const int*   __restrict__ neighbor_bits,
    float*       __restrict__ out,
    int T, int T4 /* = T/4 */)
{
    int t4 = blockIdx.x * blockDim.x + threadIdx.x;
    if (t4 >= T4) return;
    const long long row = blockIdx.y;            // one (b,c) row per grid.y
    const int t0 = t4 * 4;

    const float* __restrict__ xrow = x + row * (long long)T;

    float4 v = *reinterpret_cast<const float4*>(xrow + t0);          // coalesced 16B
    int4   m = *reinterpret_cast<const int4*>(replace_mask + t0);    // L1-resident tables
    int4   b = *reinterpret_cast<const int4*>(neighbor_bits + t0);

    const int lane = threadIdx.x & 63;
    float left  = __shfl_up(v.w, 1);    // element t0-1 (prev lane's v.w)
    float right = __shfl_down(v.x, 1);  // element t0+4 (next lane's v.x)
    if (lane == 0)  left  = xrow[t0 > 0 ? t0 - 1 : 0];       // wave edge; t0==0 case unused
    if (lane == 63) right = xrow[t0 + 4 < T ? t0 + 4 : T-1]; // wave edge; t0+4==T case unused

    // j=0: t==0 -> v.y ; off=+1 -> v.y ; off=-1 -> left
    float o0 = m.x ? ((t0 == 0 || b.x > 0) ? v.y : left)  : v.x;
    // j=1: off=+1 -> v.z ; off=-1 -> v.x
    float o1 = m.y ? ((b.y > 0) ? v.z : v.x)              : v.y;
    // j=2: off=+1 -> v.w ; off=-1 -> v.y
    float o2 = m.z ? ((b.z > 0) ? v.w : v.y)              : v.z;
    // j=3: t==T-1 -> v.z (=T-2) ; off=-1 -> v.z ; off=+1 -> right
    float o3 = m.w ? ((t0 + 4 == T || b.w <= 0) ? v.z : right) : v.w;

    *reinterpret_cast<float4*>(out + row * (long long)T + t0) = float4{o0, o1, o2, o3};
}

extern "C" void kernel_launch(void* const* d_in, const int* in_sizes, int n_in,
                              void* d_out, int out_size, void* d_ws, size_t ws_size,
                              hipStream_t stream) {
    const float* x             = (const float*)d_in[0];
    const int*   replace_mask  = (const int*)d_in[1];
    const int*   neighbor_bits = (const int*)d_in[2];
    float*       out           = (float*)d_out;

    const int T    = in_sizes[1];          // 4000
    const int rows = in_sizes[0] / T;      // B*C = 16384
    const int T4   = T / 4;                // 1000

    dim3 block(256, 1, 1);
    dim3 grid((T4 + 255) / 256, rows, 1);  // (4, 16384)
    Jitter_84765474553865_kernel<<<grid, block, 0, stream>>>(
        x, replace_mask, neighbor_bits, out, T, T4);
}